// Round 16
// baseline (497.713 us; speedup 1.0000x reference)
//
#include <hip/hip_runtime.h>
#include <hip/hip_bf16.h>

#define N_NODES 200000
#define N_EDGES 500000
#define F_IN    165
#define HIDDEN  384
#define F_OUT   2

#define KPAD1   192          // F_IN padded to multiple of 32
#define M_TILES 1563         // ceil(200000/128)
#define M_PAD   (M_TILES * 128)
#define NB_SCAN 782          // ceil(200000/256)
#define GRID_GEMM (196 * 24) // ceil(1563/8) groups * (3 cols * 8 panels)

typedef unsigned short ushort_t;
typedef unsigned int   uint_t;

using bf16x8 = __attribute__((ext_vector_type(8))) short;
using f32x4  = __attribute__((ext_vector_type(4))) float;

__device__ __forceinline__ float bf2f(uint_t u) {
    return __uint_as_float(u << 16);
}
__device__ __forceinline__ ushort_t f2bf(float x) {
    uint_t b = __float_as_uint(x);
    return (ushort_t)((b + 0x7FFFu + ((b >> 16) & 1u)) >> 16);  // RNE
}

// async 16B/lane global->LDS DMA; lds dest = wave-uniform base + lane*16
__device__ __forceinline__ void async16(const ushort_t* g, ushort_t* l) {
    __builtin_amdgcn_global_load_lds(
        (const __attribute__((address_space(1))) void*)g,
        (__attribute__((address_space(3))) void*)l,
        16, 0, 0);
}

// ---------------------------------------------------------------------------
// degree count (in-degree via col), int atomics into `cnt`
// ---------------------------------------------------------------------------
__global__ void count_kernel(const int* __restrict__ col, int* __restrict__ cnt, int E) {
    int e = blockIdx.x * blockDim.x + threadIdx.x;
    if (e < E) atomicAdd(&cnt[col[e]], 1);
}

__global__ void dinv_kernel(const int* __restrict__ cnt, float* __restrict__ dinv, int n) {
    int i = blockIdx.x * blockDim.x + threadIdx.x;
    if (i < n) dinv[i] = rsqrtf((float)(cnt[i] + 1));   // +1 self loop
}

// ---------------------------------------------------------------------------
// two-level exclusive scan of cnt[0..N) -> ptr (local prefix), bsum (block sums)
// ---------------------------------------------------------------------------
__global__ __launch_bounds__(256) void scan1_kernel(const int* __restrict__ cnt,
                                                    int* __restrict__ loc,
                                                    int* __restrict__ bsum, int N) {
    __shared__ int sh[256];
    int t = threadIdx.x;
    int i = blockIdx.x * 256 + t;
    int v = (i < N) ? cnt[i] : 0;
    sh[t] = v;
    __syncthreads();
    #pragma unroll
    for (int off = 1; off < 256; off <<= 1) {
        int u = (t >= off) ? sh[t - off] : 0;
        __syncthreads();
        sh[t] += u;
        __syncthreads();
    }
    int incl = sh[t];
    if (i < N) loc[i] = incl - v;            // exclusive local prefix
    if (t == 255) bsum[blockIdx.x] = incl;   // block total
}

__global__ __launch_bounds__(1024) void scan2_kernel(int* __restrict__ bsum, int NB) {
    __shared__ int sh[1024];
    int t = threadIdx.x;
    int v = (t < NB) ? bsum[t] : 0;
    sh[t] = v;
    __syncthreads();
    #pragma unroll
    for (int off = 1; off < 1024; off <<= 1) {
        int u = (t >= off) ? sh[t - off] : 0;
        __syncthreads();
        sh[t] += u;
        __syncthreads();
    }
    if (t < NB) bsum[t] = sh[t] - v;         // exclusive
}

__global__ __launch_bounds__(256) void scan3_kernel(int* __restrict__ ptr,
                                                    int* __restrict__ cursor,
                                                    const int* __restrict__ bsum,
                                                    int N, int E) {
    int t = threadIdx.x;
    int i = blockIdx.x * 256 + t;
    if (i < N) {
        int p = ptr[i] + bsum[blockIdx.x];
        ptr[i] = p;
        cursor[i] = p;
    }
    if (i == 0) ptr[N] = E;
}

// ---------------------------------------------------------------------------
// scatter edges into CSR-by-col order; nrm = dinv[r]*dinv[c]
// ---------------------------------------------------------------------------
__global__ void scatter_kernel(const int* __restrict__ row, const int* __restrict__ col,
                               const float* __restrict__ dinv,
                               int* __restrict__ cursor,
                               int* __restrict__ row_srt, float* __restrict__ nrm_srt, int E) {
    int e = blockIdx.x * blockDim.x + threadIdx.x;
    if (e >= E) return;
    int r = row[e], c = col[e];
    int pos = atomicAdd(&cursor[c], 1);
    row_srt[pos] = r;
    nrm_srt[pos] = dinv[r] * dinv[c];
}

// ---------------------------------------------------------------------------
// convert X fp32 [N][165] -> bf16 [N][192] (zero pad), rows 64B-aligned.
// ---------------------------------------------------------------------------
__global__ void convx_kernel(const float* __restrict__ X, uint_t* __restrict__ Xb, int total) {
    int idx = blockIdx.x * blockDim.x + threadIdx.x;   // over N*96
    if (idx >= total) return;
    int node = idx / 96, ui = idx - node * 96;
    int f = ui * 2;
    const float* xr = X + (size_t)node * F_IN;
    float lo = (f < F_IN) ? xr[f] : 0.0f;
    float hi = (f + 1 < F_IN) ? xr[f + 1] : 0.0f;
    Xb[idx] = (uint_t)f2bf(lo) | ((uint_t)f2bf(hi) << 16);
}

// ---------------------------------------------------------------------------
// agg for bf16 X (stride 96 uints) -> bf16 out, stride KPAD1. wave per node.
// ---------------------------------------------------------------------------
__global__ __launch_bounds__(256) void agg165b_kernel(
        const uint_t* __restrict__ Xb, const float* __restrict__ dinv,
        const int* __restrict__ ptr, const int* __restrict__ row_srt,
        const float* __restrict__ nrm_srt, ushort_t* __restrict__ out, int N) {
    int w    = (blockIdx.x * blockDim.x + threadIdx.x) >> 6;
    int lane = threadIdx.x & 63;
    if (w >= N) return;
    float d2 = dinv[w]; d2 *= d2;
    const uint_t* self = Xb + (size_t)w * 96;
    bool two = (lane < 19);                    // uints 64..82 cover f 128..165
    uint_t u0 = self[lane];
    uint_t u1 = two ? self[64 + lane] : 0u;
    float ax0 = bf2f(u0 & 0xFFFFu) * d2, ay0 = bf2f(u0 >> 16) * d2;
    float ax1 = bf2f(u1 & 0xFFFFu) * d2, ay1 = bf2f(u1 >> 16) * d2;
    int e0 = ptr[w], e1 = ptr[w + 1];
    for (int e = e0; e < e1; ++e) {
        int r = row_srt[e];
        float wg = nrm_srt[e];
        const uint_t* hr = Xb + (size_t)r * 96;
        uint_t v0 = hr[lane];
        uint_t v1 = two ? hr[64 + lane] : 0u;
        ax0 = fmaf(bf2f(v0 & 0xFFFFu), wg, ax0);
        ay0 = fmaf(bf2f(v0 >> 16), wg, ay0);
        ax1 = fmaf(bf2f(v1 & 0xFFFFu), wg, ax1);
        ay1 = fmaf(bf2f(v1 >> 16), wg, ay1);
    }
    uint_t* o = (uint_t*)(out + (size_t)w * KPAD1);
    o[lane] = (uint_t)f2bf(ax0) | ((uint_t)f2bf(ay0) << 16);
    if (two) o[64 + lane] = (uint_t)f2bf(ax1) | ((uint_t)f2bf(ay1) << 16);
}

// ---------------------------------------------------------------------------
// agg for bf16 H (F=384, stride 384) -> bf16 out (stride 384)
// ---------------------------------------------------------------------------
__global__ __launch_bounds__(256) void agg384_kernel(
        const ushort_t* __restrict__ H, const float* __restrict__ dinv,
        const int* __restrict__ ptr, const int* __restrict__ row_srt,
        const float* __restrict__ nrm_srt, ushort_t* __restrict__ out, int N) {
    int w    = (blockIdx.x * blockDim.x + threadIdx.x) >> 6;
    int lane = threadIdx.x & 63;
    if (w >= N) return;
    float d2 = dinv[w]; d2 *= d2;
    const uint_t* self = (const uint_t*)(H + (size_t)w * HIDDEN);
    float ax[3], ay[3];
    #pragma unroll
    for (int j = 0; j < 3; ++j) {
        uint_t u = self[lane + 64 * j];
        ax[j] = bf2f(u & 0xFFFFu) * d2;
        ay[j] = bf2f(u >> 16) * d2;
    }
    int e0 = ptr[w], e1 = ptr[w + 1];
    for (int e = e0; e < e1; ++e) {
        int r = row_srt[e];
        float wg = nrm_srt[e];
        const uint_t* hr = (const uint_t*)(H + (size_t)r * HIDDEN);
        #pragma unroll
        for (int j = 0; j < 3; ++j) {
            uint_t u = hr[lane + 64 * j];
            ax[j] = fmaf(bf2f(u & 0xFFFFu), wg, ax[j]);
            ay[j] = fmaf(bf2f(u >> 16), wg, ay[j]);
        }
    }
    uint_t* o = (uint_t*)(out + (size_t)w * HIDDEN);
    #pragma unroll
    for (int j = 0; j < 3; ++j)
        o[lane + 64 * j] = (uint_t)f2bf(ax[j]) | ((uint_t)f2bf(ay[j]) << 16);
}

// ---------------------------------------------------------------------------
// weight prep: Wt[n][k] = bf16(W[k][n]), zero pad for k >= Kin
// ---------------------------------------------------------------------------
__global__ void prep_wt_kernel(const float* __restrict__ W, ushort_t* __restrict__ Wt,
                               int Kin, int Kpad, int Nn) {
    int idx = blockIdx.x * blockDim.x + threadIdx.x;
    if (idx >= Nn * Kpad) return;
    int n = idx / Kpad, k = idx - n * Kpad;
    float v = (k < Kin) ? W[(size_t)k * Nn + n] : 0.0f;
    Wt[idx] = f2bf(v);
}

// ---------------------------------------------------------------------------
// MFMA bf16 GEMM (layer 1): C = relu(A @ Wt^T + bias), bf16 C store.
// 128x128 tile, BK=32, 4 waves, global_load_lds 3-deep counted-vmcnt pipeline,
// source-side XOR swizzle, XCD-coherent 1D grid swizzle.
// ---------------------------------------------------------------------------
#define GBK 32

template<bool RELU>
__global__ __launch_bounds__(256) void mfma_gemm_kernel(
        const ushort_t* __restrict__ A, const ushort_t* __restrict__ Wt,
        const float* __restrict__ bias, ushort_t* __restrict__ C,
        int Ks, int Nn, int nTilesM) {
    __shared__ ushort_t As[3][128 * GBK];
    __shared__ ushort_t Bs[3][128 * GBK];

    const int l  = blockIdx.x;
    const int g  = l / 24;
    const int r_ = l - g * 24;
    const int cb = r_ >> 3;
    const int pm = r_ & 7;
    const int pt = g * 8 + pm;
    if (pt >= nTilesM) return;
    const int bm = pt * 128;
    const int bn = cb * 128;

    const int tid  = threadIdx.x;
    const int lane = tid & 63;
    const int w    = tid >> 6;
    const int wm   = w & 1;
    const int wn   = w >> 1;

    auto brow = [](int s) {
        return ((s >> 6) * 64) + ((s & 63) >> 4) + ((s & 15) * 4);
    };

    const int r0  = w * 32;
    const int s0  = r0 + (lane >> 2);
    const int s1  = s0 + 16;
    const int c0  = (lane & 3) ^ ((s0 >> 1) & 3);
    const int c1  = (lane & 3) ^ ((s1 >> 1) & 3);

    const ushort_t* gA0 = A + (size_t)(bm + s0) * Ks + c0 * 8;
    const ushort_t* gA1 = A + (size_t)(bm + s1) * Ks + c1 * 8;
    const ushort_t* gB0 = Wt + (size_t)(bn + brow(s0)) * Ks + c0 * 8;
    const ushort_t* gB1 = Wt + (size_t)(bn + brow(s1)) * Ks + c1 * 8;

    const int p     = lane & 15;
    const int khalf = lane >> 4;
    const int qf    = khalf ^ ((p >> 1) & 3);
    int aoff[4], boff[4];
    #pragma unroll
    for (int f = 0; f < 4; ++f) {
        aoff[f] = (wm * 64 + f * 16 + p) * GBK + qf * 8;
        boff[f] = (wn * 64 + f * 16 + p) * GBK + qf * 8;
    }

    f32x4 acc[4][4] = {};

    const int ksteps = Ks >> 5;
    #pragma unroll
    for (int t = 0; t < 3; ++t) {
        if (t < ksteps) {
            const int ko = t * GBK;
            async16(gA0 + ko, &As[t][r0 * GBK]);
            async16(gA1 + ko, &As[t][(r0 + 16) * GBK]);
            async16(gB0 + ko, &Bs[t][r0 * GBK]);
            async16(gB1 + ko, &Bs[t][(r0 + 16) * GBK]);
        }
    }

    int cur = 0;
    for (int kt = 0; kt < ksteps; ++kt) {
        const int ahead = ((ksteps - kt) < 3 ? (ksteps - kt) : 3) - 1;
        if (ahead == 2)      asm volatile("s_waitcnt vmcnt(8)" ::: "memory");
        else if (ahead == 1) asm volatile("s_waitcnt vmcnt(4)" ::: "memory");
        else                 asm volatile("s_waitcnt vmcnt(0)" ::: "memory");
        asm volatile("s_barrier" ::: "memory");

        const ushort_t* Ab = As[cur];
        const ushort_t* Bb = Bs[cur];
        bf16x8 af[4], bfr[4];
        #pragma unroll
        for (int f = 0; f < 4; ++f) {
            af[f]  = *reinterpret_cast<const bf16x8*>(&Ab[aoff[f]]);
            bfr[f] = *reinterpret_cast<const bf16x8*>(&Bb[boff[f]]);
        }
        #pragma unroll
        for (int mi = 0; mi < 4; ++mi)
            #pragma unroll
            for (int ni = 0; ni < 4; ++ni)
                acc[mi][ni] = __builtin_amdgcn_mfma_f32_16x16x32_bf16(
                    af[mi], bfr[ni], acc[mi][ni], 0, 0, 0);

        asm volatile("s_barrier" ::: "memory");
        if (kt + 3 < ksteps) {
            const int ko = (kt + 3) * GBK;
            async16(gA0 + ko, &As[cur][r0 * GBK]);
            async16(gA1 + ko, &As[cur][(r0 + 16) * GBK]);
            async16(gB0 + ko, &Bs[cur][r0 * GBK]);
            async16(gB1 + ko, &Bs[cur][(r0 + 16) * GBK]);
        }
        cur = (cur == 2) ? 0 : cur + 1;
    }

    const int colbase = bn + wn * 64 + p * 4;
    const float4 bb = *reinterpret_cast<const float4*>(bias + colbase);
    const float bias4[4] = {bb.x, bb.y, bb.z, bb.w};
    #pragma unroll
    for (int mi = 0; mi < 4; ++mi) {
        const int rowbase = bm + wm * 64 + mi * 16 + khalf * 4;
        #pragma unroll
        for (int j = 0; j < 4; ++j) {
            float v0 = acc[mi][0][j] + bias4[0];
            float v1 = acc[mi][1][j] + bias4[1];
            float v2 = acc[mi][2][j] + bias4[2];
            float v3 = acc[mi][3][j] + bias4[3];
            if (RELU) {
                v0 = fmaxf(v0, 0.f); v1 = fmaxf(v1, 0.f);
                v2 = fmaxf(v2, 0.f); v3 = fmaxf(v3, 0.f);
            }
            ushort4 o;
            o.x = f2bf(v0); o.y = f2bf(v1); o.z = f2bf(v2); o.w = f2bf(v3);
            *reinterpret_cast<ushort4*>(C + (size_t)(rowbase + j) * Nn + colbase) = o;
        }
    }
}

// ---------------------------------------------------------------------------
// MFMA bf16 GEMM (layer 2+3 fused): H2 = relu(Ha @ Wt2^T + b2) kept in regs,
// G[r,0:2] += H2_tile @ W3 via shfl-reduce + atomics. NO C store.
// (known-good r13 build: passed validation + tripwire + graph at 496 us)
// ---------------------------------------------------------------------------
__global__ __launch_bounds__(256) void mfma_gemm_fused_kernel(
        const ushort_t* __restrict__ A, const ushort_t* __restrict__ Wt,
        const float* __restrict__ bias, const float* __restrict__ W3,
        float* __restrict__ G, int Ks, int Nn, int nTilesM) {
    __shared__ ushort_t As[3][128 * GBK];
    __shared__ ushort_t Bs[3][128 * GBK];

    const int l  = blockIdx.x;
    const int g  = l / 24;
    const int r_ = l - g * 24;
    const int cb = r_ >> 3;
    const int pm = r_ & 7;
    const int pt = g * 8 + pm;
    if (pt >= nTilesM) return;
    const int bm = pt * 128;
    const int bn = cb * 128;

    const int tid  = threadIdx.x;
    const int lane = tid & 63;
    const int w    = tid >> 6;
    const int wm   = w & 1;
    const int wn   = w >> 1;

    auto brow = [](int s) {
        return ((s >> 6) * 64) + ((s & 63) >> 4) + ((s & 15) * 4);
    };

    const int r0  = w * 32;
    const int s0  = r0 + (lane >> 2);
    const int s1  = s0 + 16;
    const int c0  = (lane & 3) ^ ((s0 >> 1) & 3);
    const int c1  = (lane & 3) ^ ((s1 >> 1) & 3);

    const ushort_t* gA0 = A + (size_t)(bm + s0) * Ks + c0 * 8;
    const ushort_t* gA1 = A + (size_t)(bm + s1) * Ks + c1 * 8;
    const ushort_t* gB0 = Wt + (size_t)(bn + brow(s0)) * Ks + c0 * 8;
    const ushort_t* gB1 = Wt + (size_t)(bn + brow(s1)) * Ks + c1 * 8;

    const int p     = lane & 15;
    const int khalf = lane >> 4;
    const int qf    = khalf ^ ((p >> 1) & 3);
    int aoff[4], boff[4];
    #pragma unroll
    for (int f = 0; f < 4; ++f) {
        aoff[f] = (wm * 64 + f * 16 + p) * GBK + qf * 8;
        boff[f] = (wn * 64 + f * 16 + p) * GBK + qf * 8;
    }

    f32x4 acc[4][4] = {};

    const int ksteps = Ks >> 5;
    #pragma unroll
    for (int t = 0; t < 3; ++t) {
        if (t < ksteps) {
            const int ko = t * GBK;
            async16(gA0 + ko, &As[t][r0 * GBK]);
            async16(gA1 + ko, &As[t][(r0 + 16) * GBK]);
            async16(gB0 + ko, &Bs[t][r0 * GBK]);
            async16(gB1 + ko, &Bs[t][(r0 + 16) * GBK]);
        }
    }

    int cur = 0;
    for (int kt = 0; kt < ksteps; ++kt) {
        const int ahead = ((ksteps - kt) < 3 ? (ksteps - kt) : 3) - 1;
        if (ahead == 2)      asm volatile("s_waitcnt vmcnt(8)" ::: "memory");
        else if (ahead == 1) asm volatile("s_waitcnt vmcnt(4)" ::: "memory");
        else                 asm volatile("s_waitcnt vmcnt(0)" ::: "memory");
        asm volatile("s_barrier" ::: "memory");

        const ushort_t* Ab = As[cur];
        const ushort_t* Bb = Bs[cur];
        bf16x8 af[4], bfr[4];
        #pragma unroll
        for (int f = 0; f < 4; ++f) {
            af[f]  = *reinterpret_cast<const bf16x8*>(&Ab[aoff[f]]);
            bfr[f] = *reinterpret_cast<const bf16x8*>(&Bb[boff[f]]);
        }
        #pragma unroll
        for (int mi = 0; mi < 4; ++mi)
            #pragma unroll
            for (int ni = 0; ni < 4; ++ni)
                acc[mi][ni] = __builtin_amdgcn_mfma_f32_16x16x32_bf16(
                    af[mi], bfr[ni], acc[mi][ni], 0, 0, 0);

        asm volatile("s_barrier" ::: "memory");
        if (kt + 3 < ksteps) {
            const int ko = (kt + 3) * GBK;
            async16(gA0 + ko, &As[cur][r0 * GBK]);
            async16(gA1 + ko, &As[cur][(r0 + 16) * GBK]);
            async16(gB0 + ko, &Bs[cur][r0 * GBK]);
            async16(gB1 + ko, &Bs[cur][(r0 + 16) * GBK]);
        }
        cur = (cur == 2) ? 0 : cur + 1;
    }

    // ---- fused epilogue: G[r] += relu(acc + b2) @ W3 ----
    const int colbase = bn + wn * 64 + p * 4;
    const float4 bb = *reinterpret_cast<const float4*>(bias + colbase);
    const float bias4[4] = {bb.x, bb.y, bb.z, bb.w};
    float w30[4], w31[4];
    #pragma unroll
    for (int ni = 0; ni < 4; ++ni) {
        w30[ni] = W3[(size_t)(colbase + ni) * 2 + 0];
        w31[ni] = W3[(size_t)(colbase + ni) * 2 + 1];
    }
    #pragma unroll
    for (int mi = 0; mi < 4; ++mi) {
        const int rowbase = bm + wm * 64 + mi * 16 + khalf * 4;
        #pragma unroll
        for (int j = 0; j < 4; ++j) {
            float g0 = 0.f, g1 = 0.f;
            #pragma unroll
            for (int ni = 0; ni < 4; ++ni) {
                float h = fmaxf(acc[mi][ni][j] + bias4[ni], 0.f);
                g0 = fmaf(h, w30[ni], g0);
                g1 = fmaf(h, w31[ni], g1);
            }
            // reduce over the 16 col-lanes (p); xor masks stay within group
            #pragma unroll
            for (int m = 1; m < 16; m <<= 1) {
                g0 += __shfl_xor(g0, m);
                g1 += __shfl_xor(g1, m);
            }
            const int r = rowbase + j;
            if (p == 0 && r < N_NODES) {
                atomicAdd(&G[(size_t)r * 2 + 0], g0);
                atomicAdd(&G[(size_t)r * 2 + 1], g1);
            }
        }
    }
}

// ---------------------------------------------------------------------------
// final: out[i,:] = dinv[i]^2*G[i,:] + sum_e nrm_e*G[row_e,:] + b3
// ---------------------------------------------------------------------------
__global__ void out_kernel(const float* __restrict__ G, const float* __restrict__ dinv,
                           const int* __restrict__ ptr, const int* __restrict__ row_srt,
                           const float* __restrict__ nrm_srt, const float* __restrict__ b3,
                           float* __restrict__ out, int N) {
    int i = blockIdx.x * blockDim.x + threadIdx.x;
    if (i >= N) return;
    float d2 = dinv[i]; d2 *= d2;
    float a0 = G[(size_t)i * 2 + 0] * d2 + b3[0];
    float a1 = G[(size_t)i * 2 + 1] * d2 + b3[1];
    int e0 = ptr[i], e1 = ptr[i + 1];
    for (int e = e0; e < e1; ++e) {
        int r = row_srt[e];
        float wg = nrm_srt[e];
        a0 = fmaf(G[(size_t)r * 2 + 0], wg, a0);
        a1 = fmaf(G[(size_t)r * 2 + 1], wg, a1);
    }
    out[(size_t)i * 2 + 0] = a0;
    out[(size_t)i * 2 + 1] = a1;
}

// ---------------------------------------------------------------------------
extern "C" void kernel_launch(void* const* d_in, const int* in_sizes, int n_in,
                              void* d_out, int out_size, void* d_ws, size_t ws_size,
                              hipStream_t stream) {
    const float* x   = (const float*)d_in[0];
    const int*   ei  = (const int*)  d_in[1];   // [2, E]
    const float* W1  = (const float*)d_in[2];
    const float* b1  = (const float*)d_in[3];
    const float* W2  = (const float*)d_in[4];
    const float* b2  = (const float*)d_in[5];
    const float* W3  = (const float*)d_in[6];
    const float* b3  = (const float*)d_in[7];
    float* out = (float*)d_out;

    const int N = N_NODES, E = N_EDGES;
    const int* row = ei;
    const int* col = ei + E;

    // ---- workspace layout (bytes, 256-aligned chunks) ----
    size_t off = 0;
    auto alloc = [&](size_t bytes) { size_t o = off; off += (bytes + 255) & ~(size_t)255; return o; };
    size_t o_dinv   = alloc((size_t)N * 4);
    size_t o_ptr    = alloc((size_t)(N + 1) * 4);
    size_t o_cnt    = alloc((size_t)N * 4);
    size_t o_cursor = alloc((size_t)N * 4);
    size_t o_bsum   = alloc((size_t)NB_SCAN * 4);
    size_t o_rowsrt = alloc((size_t)E * 4);
    size_t o_nrmsrt = alloc((size_t)E * 4);
    size_t o_G      = alloc((size_t)N * 2 * 4);
    size_t o_Wt1    = alloc((size_t)HIDDEN * KPAD1 * 2);
    size_t o_Wt2    = alloc((size_t)HIDDEN * HIDDEN * 2);
    size_t o_B1     = alloc((size_t)M_PAD * HIDDEN * 2);   // bf16: Xa(stride 192) then Ha(384)
    size_t o_B2     = alloc((size_t)M_PAD * HIDDEN * 2);   // bf16: Xb alias, then H1
    if (ws_size < off) return;   // visible zero-output failure if too small

    char* ws = (char*)d_ws;
    float*    dinv    = (float*)(ws + o_dinv);
    int*      ptr     = (int*)  (ws + o_ptr);
    int*      cnt     = (int*)  (ws + o_cnt);
    int*      cursor  = (int*)  (ws + o_cursor);
    int*      bsum    = (int*)  (ws + o_bsum);
    int*      row_srt = (int*)  (ws + o_rowsrt);
    float*    nrm_srt = (float*)(ws + o_nrmsrt);
    float*    G       = (float*)(ws + o_G);
    ushort_t* Wt1     = (ushort_t*)(ws + o_Wt1);
    ushort_t* Wt2     = (ushort_t*)(ws + o_Wt2);
    ushort_t* B1      = (ushort_t*)(ws + o_B1);
    ushort_t* B2      = (ushort_t*)(ws + o_B2);
    uint_t*   Xb      = (uint_t*)B2;   // bf16 X, [N][96] uints; dead once GEMM1 writes H1

    const int B = 256;

    // 0. weight prep (bf16 transpose, zero-padded K) + X bf16 conversion
    prep_wt_kernel<<<(HIDDEN * KPAD1 + B - 1) / B, B, 0, stream>>>(W1, Wt1, F_IN, KPAD1, HIDDEN);
    prep_wt_kernel<<<(HIDDEN * HIDDEN + B - 1) / B, B, 0, stream>>>(W2, Wt2, HIDDEN, HIDDEN, HIDDEN);
    convx_kernel<<<(N * 96 + B - 1) / B, B, 0, stream>>>(x, Xb, N * 96);

    // 1. CSR build + dinv (two-level parallel scan); zero G for fused atomics
    hipMemsetAsync(cnt, 0, (size_t)N * 4, stream);
    hipMemsetAsync(G, 0, (size_t)N * 2 * 4, stream);
    count_kernel<<<(E + B - 1) / B, B, 0, stream>>>(col, cnt, E);
    dinv_kernel<<<(N + B - 1) / B, B, 0, stream>>>(cnt, dinv, N);
    scan1_kernel<<<NB_SCAN, 256, 0, stream>>>(cnt, ptr, bsum, N);
    scan2_kernel<<<1, 1024, 0, stream>>>(bsum, NB_SCAN);
    scan3_kernel<<<NB_SCAN, 256, 0, stream>>>(ptr, cursor, bsum, N, E);
    scatter_kernel<<<(E + B - 1) / B, B, 0, stream>>>(row, col, dinv, cursor, row_srt, nrm_srt, E);

    // 2. Xa = A @ Xb -> B1 (bf16, stride KPAD1); 6-line aligned gathers
    agg165b_kernel<<<(N * 64 + B - 1) / B, B, 0, stream>>>(Xb, dinv, ptr, row_srt, nrm_srt, B1, N);

    // 3. H1 = relu(Xa @ W1 + b1) -> B2 (overwrites Xb, which is now dead)
    mfma_gemm_kernel<true><<<GRID_GEMM, 256, 0, stream>>>(B1, Wt1, b1, B2, KPAD1, HIDDEN, M_TILES);

    // 4. Ha = A @ H1 -> B1 (stride 384)
    agg384_kernel<<<(N * 64 + B - 1) / B, B, 0, stream>>>(B2, dinv, ptr, row_srt, nrm_srt, B1, N);

    // 5+6. G = relu(Ha @ W2 + b2) @ W3  (fused; no H2 materialization)
    mfma_gemm_fused_kernel<<<GRID_GEMM, 256, 0, stream>>>(B1, Wt2, b2, W3, G, HIDDEN, HIDDEN, M_TILES);

    // 7. out = A @ G + b3
    out_kernel<<<(N + B - 1) / B, B, 0, stream>>>(G, dinv, ptr, row_srt, nrm_srt, b3, out, N);
}

// Round 19
// 472.760 us; speedup vs baseline: 1.0528x; 1.0528x over previous
//
#include <hip/hip_runtime.h>
#include <hip/hip_bf16.h>

#define N_NODES 200000
#define N_EDGES 500000
#define F_IN    165
#define HIDDEN  384
#define F_OUT   2

#define KPAD1   192          // F_IN padded to multiple of 32
#define M_TILES 1563         // ceil(200000/128)
#define M_PAD   (M_TILES * 128)
#define NB_SCAN 782          // ceil(200000/256)
#define GRID_GEMM (196 * 24) // ceil(1563/8) groups * (3 cols * 8 panels)

typedef unsigned short ushort_t;
typedef unsigned int   uint_t;

using bf16x8 = __attribute__((ext_vector_type(8))) short;
using f32x4  = __attribute__((ext_vector_type(4))) float;

__device__ __forceinline__ float bf2f(uint_t u) {
    return __uint_as_float(u << 16);
}
__device__ __forceinline__ ushort_t f2bf(float x) {
    uint_t b = __float_as_uint(x);
    return (ushort_t)((b + 0x7FFFu + ((b >> 16) & 1u)) >> 16);  // RNE
}

// async 16B/lane global->LDS DMA; lds dest = wave-uniform base + lane*16
__device__ __forceinline__ void async16(const ushort_t* g, ushort_t* l) {
    __builtin_amdgcn_global_load_lds(
        (const __attribute__((address_space(1))) void*)g,
        (__attribute__((address_space(3))) void*)l,
        16, 0, 0);
}

// ---------------------------------------------------------------------------
// degree count (in-degree via col), int atomics into `cnt`
// ---------------------------------------------------------------------------
__global__ void count_kernel(const int* __restrict__ col, int* __restrict__ cnt, int E) {
    int e = blockIdx.x * blockDim.x + threadIdx.x;
    if (e < E) atomicAdd(&cnt[col[e]], 1);
}

__global__ void dinv_kernel(const int* __restrict__ cnt, float* __restrict__ dinv, int n) {
    int i = blockIdx.x * blockDim.x + threadIdx.x;
    if (i < n) dinv[i] = rsqrtf((float)(cnt[i] + 1));   // +1 self loop
}

// ---------------------------------------------------------------------------
// two-level exclusive scan of cnt[0..N) -> ptr (local prefix), bsum (block sums)
// ---------------------------------------------------------------------------
__global__ __launch_bounds__(256) void scan1_kernel(const int* __restrict__ cnt,
                                                    int* __restrict__ loc,
                                                    int* __restrict__ bsum, int N) {
    __shared__ int sh[256];
    int t = threadIdx.x;
    int i = blockIdx.x * 256 + t;
    int v = (i < N) ? cnt[i] : 0;
    sh[t] = v;
    __syncthreads();
    #pragma unroll
    for (int off = 1; off < 256; off <<= 1) {
        int u = (t >= off) ? sh[t - off] : 0;
        __syncthreads();
        sh[t] += u;
        __syncthreads();
    }
    int incl = sh[t];
    if (i < N) loc[i] = incl - v;            // exclusive local prefix
    if (t == 255) bsum[blockIdx.x] = incl;   // block total
}

__global__ __launch_bounds__(1024) void scan2_kernel(int* __restrict__ bsum, int NB) {
    __shared__ int sh[1024];
    int t = threadIdx.x;
    int v = (t < NB) ? bsum[t] : 0;
    sh[t] = v;
    __syncthreads();
    #pragma unroll
    for (int off = 1; off < 1024; off <<= 1) {
        int u = (t >= off) ? sh[t - off] : 0;
        __syncthreads();
        sh[t] += u;
        __syncthreads();
    }
    if (t < NB) bsum[t] = sh[t] - v;         // exclusive
}

__global__ __launch_bounds__(256) void scan3_kernel(int* __restrict__ ptr,
                                                    int* __restrict__ cursor,
                                                    const int* __restrict__ bsum,
                                                    int N, int E) {
    int t = threadIdx.x;
    int i = blockIdx.x * 256 + t;
    if (i < N) {
        int p = ptr[i] + bsum[blockIdx.x];
        ptr[i] = p;
        cursor[i] = p;
    }
    if (i == 0) ptr[N] = E;
}

// ---------------------------------------------------------------------------
// scatter edges into CSR-by-col order; nrm = dinv[r]*dinv[c]
// ---------------------------------------------------------------------------
__global__ void scatter_kernel(const int* __restrict__ row, const int* __restrict__ col,
                               const float* __restrict__ dinv,
                               int* __restrict__ cursor,
                               int* __restrict__ row_srt, float* __restrict__ nrm_srt, int E) {
    int e = blockIdx.x * blockDim.x + threadIdx.x;
    if (e >= E) return;
    int r = row[e], c = col[e];
    int pos = atomicAdd(&cursor[c], 1);
    row_srt[pos] = r;
    nrm_srt[pos] = dinv[r] * dinv[c];
}

// ---------------------------------------------------------------------------
// convert X fp32 [N][165] -> bf16 [N][192] (zero pad), rows 64B-aligned.
// ---------------------------------------------------------------------------
__global__ void convx_kernel(const float* __restrict__ X, uint_t* __restrict__ Xb, int total) {
    int idx = blockIdx.x * blockDim.x + threadIdx.x;   // over N*96
    if (idx >= total) return;
    int node = idx / 96, ui = idx - node * 96;
    int f = ui * 2;
    const float* xr = X + (size_t)node * F_IN;
    float lo = (f < F_IN) ? xr[f] : 0.0f;
    float hi = (f + 1 < F_IN) ? xr[f + 1] : 0.0f;
    Xb[idx] = (uint_t)f2bf(lo) | ((uint_t)f2bf(hi) << 16);
}

// ---------------------------------------------------------------------------
// agg for bf16 X (stride 96 uints) -> bf16 out, stride KPAD1. wave per node.
// edge loop chunked by 4: all indices loaded, then all gathers issued (ILP).
// ---------------------------------------------------------------------------
__global__ __launch_bounds__(256) void agg165b_kernel(
        const uint_t* __restrict__ Xb, const float* __restrict__ dinv,
        const int* __restrict__ ptr, const int* __restrict__ row_srt,
        const float* __restrict__ nrm_srt, ushort_t* __restrict__ out, int N) {
    int w    = (blockIdx.x * blockDim.x + threadIdx.x) >> 6;
    int lane = threadIdx.x & 63;
    if (w >= N) return;
    float d2 = dinv[w]; d2 *= d2;
    const uint_t* self = Xb + (size_t)w * 96;
    bool two = (lane < 19);                    // uints 64..82 cover f 128..165
    uint_t u0 = self[lane];
    uint_t u1 = two ? self[64 + lane] : 0u;
    float ax0 = bf2f(u0 & 0xFFFFu) * d2, ay0 = bf2f(u0 >> 16) * d2;
    float ax1 = bf2f(u1 & 0xFFFFu) * d2, ay1 = bf2f(u1 >> 16) * d2;
    int e0 = ptr[w], e1 = ptr[w + 1];
    for (int e = e0; e < e1; e += 4) {
        int   rr[4];
        float ww[4];
        #pragma unroll
        for (int j = 0; j < 4; ++j) {
            bool valid = (e + j < e1);
            rr[j] = valid ? row_srt[e + j] : 0;
            ww[j] = valid ? nrm_srt[e + j] : 0.0f;
        }
        #pragma unroll
        for (int j = 0; j < 4; ++j) {
            const uint_t* hr = Xb + (size_t)rr[j] * 96;
            uint_t v0 = hr[lane];
            uint_t v1 = two ? hr[64 + lane] : 0u;
            ax0 = fmaf(bf2f(v0 & 0xFFFFu), ww[j], ax0);
            ay0 = fmaf(bf2f(v0 >> 16), ww[j], ay0);
            ax1 = fmaf(bf2f(v1 & 0xFFFFu), ww[j], ax1);
            ay1 = fmaf(bf2f(v1 >> 16), ww[j], ay1);
        }
    }
    uint_t* o = (uint_t*)(out + (size_t)w * KPAD1);
    o[lane] = (uint_t)f2bf(ax0) | ((uint_t)f2bf(ay0) << 16);
    if (two) o[64 + lane] = (uint_t)f2bf(ax1) | ((uint_t)f2bf(ay1) << 16);
}

// ---------------------------------------------------------------------------
// agg for bf16 H (F=384, stride 384) -> bf16 out (stride 384), chunked by 4.
// ---------------------------------------------------------------------------
__global__ __launch_bounds__(256) void agg384_kernel(
        const ushort_t* __restrict__ H, const float* __restrict__ dinv,
        const int* __restrict__ ptr, const int* __restrict__ row_srt,
        const float* __restrict__ nrm_srt, ushort_t* __restrict__ out, int N) {
    int w    = (blockIdx.x * blockDim.x + threadIdx.x) >> 6;
    int lane = threadIdx.x & 63;
    if (w >= N) return;
    float d2 = dinv[w]; d2 *= d2;
    const uint_t* self = (const uint_t*)(H + (size_t)w * HIDDEN);
    float ax[3], ay[3];
    #pragma unroll
    for (int j = 0; j < 3; ++j) {
        uint_t u = self[lane + 64 * j];
        ax[j] = bf2f(u & 0xFFFFu) * d2;
        ay[j] = bf2f(u >> 16) * d2;
    }
    int e0 = ptr[w], e1 = ptr[w + 1];
    for (int e = e0; e < e1; e += 4) {
        int   rr[4];
        float ww[4];
        #pragma unroll
        for (int c = 0; c < 4; ++c) {
            bool valid = (e + c < e1);
            rr[c] = valid ? row_srt[e + c] : 0;
            ww[c] = valid ? nrm_srt[e + c] : 0.0f;
        }
        #pragma unroll
        for (int c = 0; c < 4; ++c) {
            const uint_t* hr = (const uint_t*)(H + (size_t)rr[c] * HIDDEN);
            #pragma unroll
            for (int j = 0; j < 3; ++j) {
                uint_t u = hr[lane + 64 * j];
                ax[j] = fmaf(bf2f(u & 0xFFFFu), ww[c], ax[j]);
                ay[j] = fmaf(bf2f(u >> 16), ww[c], ay[j]);
            }
        }
    }
    uint_t* o = (uint_t*)(out + (size_t)w * HIDDEN);
    #pragma unroll
    for (int j = 0; j < 3; ++j)
        o[lane + 64 * j] = (uint_t)f2bf(ax[j]) | ((uint_t)f2bf(ay[j]) << 16);
}

// ---------------------------------------------------------------------------
// weight prep: Wt[n][k] = bf16(W[k][n]), zero pad for k >= Kin
// ---------------------------------------------------------------------------
__global__ void prep_wt_kernel(const float* __restrict__ W, ushort_t* __restrict__ Wt,
                               int Kin, int Kpad, int Nn) {
    int idx = blockIdx.x * blockDim.x + threadIdx.x;
    if (idx >= Nn * Kpad) return;
    int n = idx / Kpad, k = idx - n * Kpad;
    float v = (k < Kin) ? W[(size_t)k * Nn + n] : 0.0f;
    Wt[idx] = f2bf(v);
}

// ---------------------------------------------------------------------------
// MFMA bf16 GEMM (layer 1): C = relu(A @ Wt^T + bias), bf16 C store.
// 128x128 tile, BK=32, 4 waves, global_load_lds 3-deep counted-vmcnt pipeline,
// source-side XOR swizzle, XCD-coherent 1D grid swizzle.
// ---------------------------------------------------------------------------
#define GBK 32

template<bool RELU>
__global__ __launch_bounds__(256) void mfma_gemm_kernel(
        const ushort_t* __restrict__ A, const ushort_t* __restrict__ Wt,
        const float* __restrict__ bias, ushort_t* __restrict__ C,
        int Ks, int Nn, int nTilesM) {
    __shared__ ushort_t As[3][128 * GBK];
    __shared__ ushort_t Bs[3][128 * GBK];

    const int l  = blockIdx.x;
    const int g  = l / 24;
    const int r_ = l - g * 24;
    const int cb = r_ >> 3;
    const int pm = r_ & 7;
    const int pt = g * 8 + pm;
    if (pt >= nTilesM) return;
    const int bm = pt * 128;
    const int bn = cb * 128;

    const int tid  = threadIdx.x;
    const int lane = tid & 63;
    const int w    = tid >> 6;
    const int wm   = w & 1;
    const int wn   = w >> 1;

    auto brow = [](int s) {
        return ((s >> 6) * 64) + ((s & 63) >> 4) + ((s & 15) * 4);
    };

    const int r0  = w * 32;
    const int s0  = r0 + (lane >> 2);
    const int s1  = s0 + 16;
    const int c0  = (lane & 3) ^ ((s0 >> 1) & 3);
    const int c1  = (lane & 3) ^ ((s1 >> 1) & 3);

    const ushort_t* gA0 = A + (size_t)(bm + s0) * Ks + c0 * 8;
    const ushort_t* gA1 = A + (size_t)(bm + s1) * Ks + c1 * 8;
    const ushort_t* gB0 = Wt + (size_t)(bn + brow(s0)) * Ks + c0 * 8;
    const ushort_t* gB1 = Wt + (size_t)(bn + brow(s1)) * Ks + c1 * 8;

    const int p     = lane & 15;
    const int khalf = lane >> 4;
    const int qf    = khalf ^ ((p >> 1) & 3);
    int aoff[4], boff[4];
    #pragma unroll
    for (int f = 0; f < 4; ++f) {
        aoff[f] = (wm * 64 + f * 16 + p) * GBK + qf * 8;
        boff[f] = (wn * 64 + f * 16 + p) * GBK + qf * 8;
    }

    f32x4 acc[4][4] = {};

    const int ksteps = Ks >> 5;
    #pragma unroll
    for (int t = 0; t < 3; ++t) {
        if (t < ksteps) {
            const int ko = t * GBK;
            async16(gA0 + ko, &As[t][r0 * GBK]);
            async16(gA1 + ko, &As[t][(r0 + 16) * GBK]);
            async16(gB0 + ko, &Bs[t][r0 * GBK]);
            async16(gB1 + ko, &Bs[t][(r0 + 16) * GBK]);
        }
    }

    int cur = 0;
    for (int kt = 0; kt < ksteps; ++kt) {
        const int ahead = ((ksteps - kt) < 3 ? (ksteps - kt) : 3) - 1;
        if (ahead == 2)      asm volatile("s_waitcnt vmcnt(8)" ::: "memory");
        else if (ahead == 1) asm volatile("s_waitcnt vmcnt(4)" ::: "memory");
        else                 asm volatile("s_waitcnt vmcnt(0)" ::: "memory");
        asm volatile("s_barrier" ::: "memory");

        const ushort_t* Ab = As[cur];
        const ushort_t* Bb = Bs[cur];
        bf16x8 af[4], bfr[4];
        #pragma unroll
        for (int f = 0; f < 4; ++f) {
            af[f]  = *reinterpret_cast<const bf16x8*>(&Ab[aoff[f]]);
            bfr[f] = *reinterpret_cast<const bf16x8*>(&Bb[boff[f]]);
        }
        #pragma unroll
        for (int mi = 0; mi < 4; ++mi)
            #pragma unroll
            for (int ni = 0; ni < 4; ++ni)
                acc[mi][ni] = __builtin_amdgcn_mfma_f32_16x16x32_bf16(
                    af[mi], bfr[ni], acc[mi][ni], 0, 0, 0);

        asm volatile("s_barrier" ::: "memory");
        if (kt + 3 < ksteps) {
            const int ko = (kt + 3) * GBK;
            async16(gA0 + ko, &As[cur][r0 * GBK]);
            async16(gA1 + ko, &As[cur][(r0 + 16) * GBK]);
            async16(gB0 + ko, &Bs[cur][r0 * GBK]);
            async16(gB1 + ko, &Bs[cur][(r0 + 16) * GBK]);
        }
        cur = (cur == 2) ? 0 : cur + 1;
    }

    const int colbase = bn + wn * 64 + p * 4;
    const float4 bb = *reinterpret_cast<const float4*>(bias + colbase);
    const float bias4[4] = {bb.x, bb.y, bb.z, bb.w};
    #pragma unroll
    for (int mi = 0; mi < 4; ++mi) {
        const int rowbase = bm + wm * 64 + mi * 16 + khalf * 4;
        #pragma unroll
        for (int j = 0; j < 4; ++j) {
            float v0 = acc[mi][0][j] + bias4[0];
            float v1 = acc[mi][1][j] + bias4[1];
            float v2 = acc[mi][2][j] + bias4[2];
            float v3 = acc[mi][3][j] + bias4[3];
            if (RELU) {
                v0 = fmaxf(v0, 0.f); v1 = fmaxf(v1, 0.f);
                v2 = fmaxf(v2, 0.f); v3 = fmaxf(v3, 0.f);
            }
            ushort4 o;
            o.x = f2bf(v0); o.y = f2bf(v1); o.z = f2bf(v2); o.w = f2bf(v3);
            *reinterpret_cast<ushort4*>(C + (size_t)(rowbase + j) * Nn + colbase) = o;
        }
    }
}

// ---------------------------------------------------------------------------
// MFMA bf16 GEMM (layer 2+3 fused): H2 = relu(Ha @ Wt2^T + b2) kept in regs,
// G[r,0:2] += H2_tile @ W3 via shfl-reduce + atomics. NO C store.
// (known-good r13/r16 build)
// ---------------------------------------------------------------------------
__global__ __launch_bounds__(256) void mfma_gemm_fused_kernel(
        const ushort_t* __restrict__ A, const ushort_t* __restrict__ Wt,
        const float* __restrict__ bias, const float* __restrict__ W3,
        float* __restrict__ G, int Ks, int Nn, int nTilesM) {
    __shared__ ushort_t As[3][128 * GBK];
    __shared__ ushort_t Bs[3][128 * GBK];

    const int l  = blockIdx.x;
    const int g  = l / 24;
    const int r_ = l - g * 24;
    const int cb = r_ >> 3;
    const int pm = r_ & 7;
    const int pt = g * 8 + pm;
    if (pt >= nTilesM) return;
    const int bm = pt * 128;
    const int bn = cb * 128;

    const int tid  = threadIdx.x;
    const int lane = tid & 63;
    const int w    = tid >> 6;
    const int wm   = w & 1;
    const int wn   = w >> 1;

    auto brow = [](int s) {
        return ((s >> 6) * 64) + ((s & 63) >> 4) + ((s & 15) * 4);
    };

    const int r0  = w * 32;
    const int s0  = r0 + (lane >> 2);
    const int s1  = s0 + 16;
    const int c0  = (lane & 3) ^ ((s0 >> 1) & 3);
    const int c1  = (lane & 3) ^ ((s1 >> 1) & 3);

    const ushort_t* gA0 = A + (size_t)(bm + s0) * Ks + c0 * 8;
    const ushort_t* gA1 = A + (size_t)(bm + s1) * Ks + c1 * 8;
    const ushort_t* gB0 = Wt + (size_t)(bn + brow(s0)) * Ks + c0 * 8;
    const ushort_t* gB1 = Wt + (size_t)(bn + brow(s1)) * Ks + c1 * 8;

    const int p     = lane & 15;
    const int khalf = lane >> 4;
    const int qf    = khalf ^ ((p >> 1) & 3);
    int aoff[4], boff[4];
    #pragma unroll
    for (int f = 0; f < 4; ++f) {
        aoff[f] = (wm * 64 + f * 16 + p) * GBK + qf * 8;
        boff[f] = (wn * 64 + f * 16 + p) * GBK + qf * 8;
    }

    f32x4 acc[4][4] = {};

    const int ksteps = Ks >> 5;
    #pragma unroll
    for (int t = 0; t < 3; ++t) {
        if (t < ksteps) {
            const int ko = t * GBK;
            async16(gA0 + ko, &As[t][r0 * GBK]);
            async16(gA1 + ko, &As[t][(r0 + 16) * GBK]);
            async16(gB0 + ko, &Bs[t][r0 * GBK]);
            async16(gB1 + ko, &Bs[t][(r0 + 16) * GBK]);
        }
    }

    int cur = 0;
    for (int kt = 0; kt < ksteps; ++kt) {
        const int ahead = ((ksteps - kt) < 3 ? (ksteps - kt) : 3) - 1;
        if (ahead == 2)      asm volatile("s_waitcnt vmcnt(8)" ::: "memory");
        else if (ahead == 1) asm volatile("s_waitcnt vmcnt(4)" ::: "memory");
        else                 asm volatile("s_waitcnt vmcnt(0)" ::: "memory");
        asm volatile("s_barrier" ::: "memory");

        const ushort_t* Ab = As[cur];
        const ushort_t* Bb = Bs[cur];
        bf16x8 af[4], bfr[4];
        #pragma unroll
        for (int f = 0; f < 4; ++f) {
            af[f]  = *reinterpret_cast<const bf16x8*>(&Ab[aoff[f]]);
            bfr[f] = *reinterpret_cast<const bf16x8*>(&Bb[boff[f]]);
        }
        #pragma unroll
        for (int mi = 0; mi < 4; ++mi)
            #pragma unroll
            for (int ni = 0; ni < 4; ++ni)
                acc[mi][ni] = __builtin_amdgcn_mfma_f32_16x16x32_bf16(
                    af[mi], bfr[ni], acc[mi][ni], 0, 0, 0);

        asm volatile("s_barrier" ::: "memory");
        if (kt + 3 < ksteps) {
            const int ko = (kt + 3) * GBK;
            async16(gA0 + ko, &As[cur][r0 * GBK]);
            async16(gA1 + ko, &As[cur][(r0 + 16) * GBK]);
            async16(gB0 + ko, &Bs[cur][r0 * GBK]);
            async16(gB1 + ko, &Bs[cur][(r0 + 16) * GBK]);
        }
        cur = (cur == 2) ? 0 : cur + 1;
    }

    // ---- fused epilogue: G[r] += relu(acc + b2) @ W3 ----
    const int colbase = bn + wn * 64 + p * 4;
    const float4 bb = *reinterpret_cast<const float4*>(bias + colbase);
    const float bias4[4] = {bb.x, bb.y, bb.z, bb.w};
    float w30[4], w31[4];
    #pragma unroll
    for (int ni = 0; ni < 4; ++ni) {
        w30[ni] = W3[(size_t)(colbase + ni) * 2 + 0];
        w31[ni] = W3[(size_t)(colbase + ni) * 2 + 1];
    }
    #pragma unroll
    for (int mi = 0; mi < 4; ++mi) {
        const int rowbase = bm + wm * 64 + mi * 16 + khalf * 4;
        #pragma unroll
        for (int j = 0; j < 4; ++j) {
            float g0 = 0.f, g1 = 0.f;
            #pragma unroll
            for (int ni = 0; ni < 4; ++ni) {
                float h = fmaxf(acc[mi][ni][j] + bias4[ni], 0.f);
                g0 = fmaf(h, w30[ni], g0);
                g1 = fmaf(h, w31[ni], g1);
            }
            #pragma unroll
            for (int m = 1; m < 16; m <<= 1) {
                g0 += __shfl_xor(g0, m);
                g1 += __shfl_xor(g1, m);
            }
            const int r = rowbase + j;
            if (p == 0 && r < N_NODES) {
                atomicAdd(&G[(size_t)r * 2 + 0], g0);
                atomicAdd(&G[(size_t)r * 2 + 1], g1);
            }
        }
    }
}

// ---------------------------------------------------------------------------
// final: out[i,:] = dinv[i]^2*G[i,:] + sum_e nrm_e*G[row_e,:] + b3
// edge loop chunked by 4 for load ILP.
// ---------------------------------------------------------------------------
__global__ void out_kernel(const float* __restrict__ G, const float* __restrict__ dinv,
                           const int* __restrict__ ptr, const int* __restrict__ row_srt,
                           const float* __restrict__ nrm_srt, const float* __restrict__ b3,
                           float* __restrict__ out, int N) {
    int i = blockIdx.x * blockDim.x + threadIdx.x;
    if (i >= N) return;
    float d2 = dinv[i]; d2 *= d2;
    float a0 = G[(size_t)i * 2 + 0] * d2 + b3[0];
    float a1 = G[(size_t)i * 2 + 1] * d2 + b3[1];
    int e0 = ptr[i], e1 = ptr[i + 1];
    for (int e = e0; e < e1; e += 4) {
        int   rr[4];
        float ww[4];
        #pragma unroll
        for (int j = 0; j < 4; ++j) {
            bool valid = (e + j < e1);
            rr[j] = valid ? row_srt[e + j] : 0;
            ww[j] = valid ? nrm_srt[e + j] : 0.0f;
        }
        #pragma unroll
        for (int j = 0; j < 4; ++j) {
            a0 = fmaf(G[(size_t)rr[j] * 2 + 0], ww[j], a0);
            a1 = fmaf(G[(size_t)rr[j] * 2 + 1], ww[j], a1);
        }
    }
    out[(size_t)i * 2 + 0] = a0;
    out[(size_t)i * 2 + 1] = a1;
}

// ---------------------------------------------------------------------------
extern "C" void kernel_launch(void* const* d_in, const int* in_sizes, int n_in,
                              void* d_out, int out_size, void* d_ws, size_t ws_size,
                              hipStream_t stream) {
    const float* x   = (const float*)d_in[0];
    const int*   ei  = (const int*)  d_in[1];   // [2, E]
    const float* W1  = (const float*)d_in[2];
    const float* b1  = (const float*)d_in[3];
    const float* W2  = (const float*)d_in[4];
    const float* b2  = (const float*)d_in[5];
    const float* W3  = (const float*)d_in[6];
    const float* b3  = (const float*)d_in[7];
    float* out = (float*)d_out;

    const int N = N_NODES, E = N_EDGES;
    const int* row = ei;
    const int* col = ei + E;

    // ---- workspace layout (bytes, 256-aligned chunks) ----
    size_t off = 0;
    auto alloc = [&](size_t bytes) { size_t o = off; off += (bytes + 255) & ~(size_t)255; return o; };
    size_t o_dinv   = alloc((size_t)N * 4);
    size_t o_ptr    = alloc((size_t)(N + 1) * 4);
    size_t o_cnt    = alloc((size_t)N * 4);
    size_t o_cursor = alloc((size_t)N * 4);
    size_t o_bsum   = alloc((size_t)NB_SCAN * 4);
    size_t o_rowsrt = alloc((size_t)E * 4);
    size_t o_nrmsrt = alloc((size_t)E * 4);
    size_t o_G      = alloc((size_t)N * 2 * 4);
    size_t o_Wt1    = alloc((size_t)HIDDEN * KPAD1 * 2);
    size_t o_Wt2    = alloc((size_t)HIDDEN * HIDDEN * 2);
    size_t o_B1     = alloc((size_t)M_PAD * HIDDEN * 2);   // bf16: Xa(stride 192) then Ha(384)
    size_t o_B2     = alloc((size_t)M_PAD * HIDDEN * 2);   // bf16: Xb alias, then H1
    if (ws_size < off) return;   // visible zero-output failure if too small

    char* ws = (char*)d_ws;
    float*    dinv    = (float*)(ws + o_dinv);
    int*      ptr     = (int*)  (ws + o_ptr);
    int*      cnt     = (int*)  (ws + o_cnt);
    int*      cursor  = (int*)  (ws + o_cursor);
    int*      bsum    = (int*)  (ws + o_bsum);
    int*      row_srt = (int*)  (ws + o_rowsrt);
    float*    nrm_srt = (float*)(ws + o_nrmsrt);
    float*    G       = (float*)(ws + o_G);
    ushort_t* Wt1     = (ushort_t*)(ws + o_Wt1);
    ushort_t* Wt2     = (ushort_t*)(ws + o_Wt2);
    ushort_t* B1      = (ushort_t*)(ws + o_B1);
    ushort_t* B2      = (ushort_t*)(ws + o_B2);
    uint_t*   Xb      = (uint_t*)B2;   // bf16 X, [N][96] uints; dead once GEMM1 writes H1

    const int B = 256;

    // 0. weight prep (bf16 transpose, zero-padded K) + X bf16 conversion
    prep_wt_kernel<<<(HIDDEN * KPAD1 + B - 1) / B, B, 0, stream>>>(W1, Wt1, F_IN, KPAD1, HIDDEN);
    prep_wt_kernel<<<(HIDDEN * HIDDEN + B - 1) / B, B, 0, stream>>>(W2, Wt2, HIDDEN, HIDDEN, HIDDEN);
    convx_kernel<<<(N * 96 + B - 1) / B, B, 0, stream>>>(x, Xb, N * 96);

    // 1. CSR build + dinv (two-level parallel scan); zero G for fused atomics
    hipMemsetAsync(cnt, 0, (size_t)N * 4, stream);
    hipMemsetAsync(G, 0, (size_t)N * 2 * 4, stream);
    count_kernel<<<(E + B - 1) / B, B, 0, stream>>>(col, cnt, E);
    dinv_kernel<<<(N + B - 1) / B, B, 0, stream>>>(cnt, dinv, N);
    scan1_kernel<<<NB_SCAN, 256, 0, stream>>>(cnt, ptr, bsum, N);
    scan2_kernel<<<1, 1024, 0, stream>>>(bsum, NB_SCAN);
    scan3_kernel<<<NB_SCAN, 256, 0, stream>>>(ptr, cursor, bsum, N, E);
    scatter_kernel<<<(E + B - 1) / B, B, 0, stream>>>(row, col, dinv, cursor, row_srt, nrm_srt, E);

    // 2. Xa = A @ Xb -> B1 (bf16, stride KPAD1); chunked gathers
    agg165b_kernel<<<(N * 64 + B - 1) / B, B, 0, stream>>>(Xb, dinv, ptr, row_srt, nrm_srt, B1, N);

    // 3. H1 = relu(Xa @ W1 + b1) -> B2 (overwrites Xb, which is now dead)
    mfma_gemm_kernel<true><<<GRID_GEMM, 256, 0, stream>>>(B1, Wt1, b1, B2, KPAD1, HIDDEN, M_TILES);

    // 4. Ha = A @ H1 -> B1 (stride 384); chunked gathers
    agg384_kernel<<<(N * 64 + B - 1) / B, B, 0, stream>>>(B2, dinv, ptr, row_srt, nrm_srt, B1, N);

    // 5+6. G = relu(Ha @ W2 + b2) @ W3  (fused; no H2 materialization)
    mfma_gemm_fused_kernel<<<GRID_GEMM, 256, 0, stream>>>(B1, Wt2, b2, W3, G, HIDDEN, HIDDEN, M_TILES);

    // 7. out = A @ G + b3
    out_kernel<<<(N + B - 1) / B, B, 0, stream>>>(G, dinv, ptr, row_srt, nrm_srt, b3, out, N);
}